// Round 1
// baseline (132.146 us; speedup 1.0000x reference)
//
#include <hip/hip_runtime.h>

// z[l, c] = prior[0] * dic[1, 0, c]  for all l in [0, L)
//
// Derivation: attention = softmax over a size-1 axis == 1.0 exactly, so the
// wy/wz branches are dead. Output is a broadcast of one scaled 1024-float row.
// Pure write-bound kernel: 512 MiB stores, ~4 KiB loads.

typedef float f4 __attribute__((ext_vector_type(4)));

__global__ __launch_bounds__(256) void CausalPredictor_46462956208724_kernel(
    const float* __restrict__ dic,    // [2, 1, C] flat; dic_z = dic + C
    const float* __restrict__ prior,  // [1]
    float* __restrict__ out,          // [L, C] flat
    int rows)                         // L
{
    const int C4 = 256;               // C/4 = 1024/4
    const float p = prior[0];

    // Thread t owns column-chunk t of every row it touches. Loop-invariant value:
    const f4* dz4 = reinterpret_cast<const f4*>(dic + 1024);   // dic[1:]
    f4 v = dz4[threadIdx.x];
    v *= p;

    f4* out4 = reinterpret_cast<f4*>(out);
    // Grid-stride over rows; 256 threads * 16 B = one contiguous 4 KiB row
    // per iteration -> fully coalesced global_store_dwordx4.
    for (int row = blockIdx.x; row < rows; row += gridDim.x) {
        __builtin_nontemporal_store(v, &out4[(size_t)row * C4 + threadIdx.x]);
    }
}

extern "C" void kernel_launch(void* const* d_in, const int* in_sizes, int n_in,
                              void* d_out, int out_size, void* d_ws, size_t ws_size,
                              hipStream_t stream) {
    // setup_inputs order: x, xm, Wy_w, Wy_b, Wz_w, Wz_b, dic, prior
    const float* dic   = (const float*)d_in[6];
    const float* prior = (const float*)d_in[7];
    float* out = (float*)d_out;

    const int C = 1024;
    const int rows = out_size / C;    // L = 131072

    const int block = 256;
    const int grid = 2048;            // grid-stride: 64 rows/block
    CausalPredictor_46462956208724_kernel<<<grid, block, 0, stream>>>(dic, prior, out, rows);
}

// Round 2
// 94.715 us; speedup vs baseline: 1.3952x; 1.3952x over previous
//
#include <hip/hip_runtime.h>

// z[l, c] = prior[0] * dic[1, 0, c]  for all l in [0, L)
//
// attention = softmax over a size-1 axis == 1.0 exactly, so the wy/wz branches
// are dead. Output is a broadcast of one scaled 1024-float row -> pure
// write-stream kernel (512 MiB stores, ~4 KiB loads).
//
// R1 change vs R0: plain temporal stores (keep L2 write-combining in the
// path; fillBufferAligned hits 6.5 TB/s this way vs our 4.06 TB/s with nt)
// + contiguous 256 KiB region per block + x4 unrolled store loop for MLP.

typedef float f4 __attribute__((ext_vector_type(4)));

__global__ __launch_bounds__(256) void CausalPredictor_46462956208724_kernel(
    const float* __restrict__ dic,    // [2, 1, C] flat; dic_z = dic + C
    const float* __restrict__ prior,  // [1]
    float* __restrict__ out,          // [L, C] flat
    int rows_per_block)               // rows / gridDim.x
{
    const int C4 = 256;               // C/4 floats4 per row; blockDim.x == 256
    const float p = prior[0];

    // Thread t owns column-chunk t of every row. Loop-invariant value:
    const f4* dz4 = reinterpret_cast<const f4*>(dic + 1024);   // dic[1:]
    f4 v = dz4[threadIdx.x];
    v *= p;

    f4* out4 = reinterpret_cast<f4*>(out);
    // Block b owns rows [b*rpb, (b+1)*rpb) -- one contiguous 256 KiB region.
    size_t base = (size_t)blockIdx.x * rows_per_block * C4 + threadIdx.x;

    #pragma unroll 4
    for (int r = 0; r < rows_per_block; ++r) {
        out4[base + (size_t)r * C4] = v;   // 256 threads * 16 B = 4 KiB/row, coalesced
    }
}

extern "C" void kernel_launch(void* const* d_in, const int* in_sizes, int n_in,
                              void* d_out, int out_size, void* d_ws, size_t ws_size,
                              hipStream_t stream) {
    // setup_inputs order: x, xm, Wy_w, Wy_b, Wz_w, Wz_b, dic, prior
    const float* dic   = (const float*)d_in[6];
    const float* prior = (const float*)d_in[7];
    float* out = (float*)d_out;

    const int C = 1024;
    const int rows = out_size / C;    // L = 131072

    const int grid = 2048;            // 2048 blocks * 64 rows = 131072 rows
    const int rows_per_block = rows / grid;
    CausalPredictor_46462956208724_kernel<<<grid, 256, 0, stream>>>(dic, prior, out, rows_per_block);
}